// Round 12
// baseline (189.335 us; speedup 1.0000x reference)
//
#include <hip/hip_runtime.h>
#include <hip/hip_bf16.h>
#include <stdint.h>

// ---------------------------------------------------------------------------
// DTransformer layer on MI355X.  B=4, T=1024, D=1024, H=16, dk=64.
//   1. conv f32 -> bf16 (WEIGHTS ONLY; tokens consumed as f32 by gemm_proj)
//   2. gemm_proj: A = f32 tokens reg-staged+converted, B = bf16 weights via
//      global_load_lds.  Q,K (B,H,T,64), V -> transposed (B,H,64,T)
//   3. attn (R7 config: 256 thr, 4 waves, 16-row blocks, XCD swizzle,
//      heaviest-first, exact-even-tiered no-max-sub softmax in exp2 domain)
//   4. gemm_out: x = concat@Wo^T + bo + query   5. layernorm
// ---------------------------------------------------------------------------

typedef unsigned short ushort_t;
typedef __attribute__((ext_vector_type(8))) short short8;
typedef __attribute__((ext_vector_type(8))) unsigned short u16x8;
typedef __attribute__((ext_vector_type(4))) float f32x4;
typedef __attribute__((ext_vector_type(4))) unsigned short u16x4;
typedef __attribute__((ext_vector_type(2))) unsigned short u16x2;

#define GLB_CAST(p) ((const __attribute__((address_space(1))) void*)(p))
#define LDS_CAST(p) ((__attribute__((address_space(3))) void*)(p))

#if __has_builtin(__builtin_amdgcn_exp2f)
#define EXP2F(x) __builtin_amdgcn_exp2f(x)
#else
#define EXP2F(x) exp2f(x)
#endif

#define LOG2E 1.44269504f

__device__ __forceinline__ float b2f(ushort_t u) {
  union { unsigned int i; float f; } x; x.i = ((unsigned int)u) << 16; return x.f;
}
__device__ __forceinline__ ushort_t f2b(float f) {   // RNE via hw convert
  __hip_bfloat16 h = __float2bfloat16(f);
  return *reinterpret_cast<ushort_t*>(&h);
}
__device__ __forceinline__ float wave_sum(float v) {
  #pragma unroll
  for (int d = 32; d > 0; d >>= 1) v += __shfl_xor(v, d);
  return v;
}

// ---------------------------------------------------------------------------
// f32 -> bf16 converts for the 3 weight matrices (1024x1024 each)
// ---------------------------------------------------------------------------
__global__ void conv3_f32_bf16(const float* __restrict__ s0, const float* __restrict__ s1,
                               const float* __restrict__ s2,
                               ushort_t* __restrict__ d0, ushort_t* __restrict__ d1,
                               ushort_t* __restrict__ d2, int n4) {
  const float* src = (blockIdx.y == 0) ? s0 : (blockIdx.y == 1) ? s1 : s2;
  ushort_t*    dst = (blockIdx.y == 0) ? d0 : (blockIdx.y == 1) ? d1 : d2;
  int i = blockIdx.x * blockDim.x + threadIdx.x;
  if (i < n4) {
    const float4 v = reinterpret_cast<const float4*>(src)[i];
    u16x4 o;
    o[0] = f2b(v.x); o[1] = f2b(v.y); o[2] = f2b(v.z); o[3] = f2b(v.w);
    reinterpret_cast<u16x4*>(dst)[i] = o;
  }
}

// ---------------------------------------------------------------------------
// Projection GEMM core with f32 A (reg-staged + converted) and bf16 B^T
// (global_load_lds).  C[m,n] = sum_k A[m,k]*Bt[n,k].  128x128 tile.
// ---------------------------------------------------------------------------
__device__ __forceinline__ void gemm_core_f32A(const float* __restrict__ A,
                                               const ushort_t* __restrict__ Bt,
                                               int m0, int n0,
                                               ushort_t* As, ushort_t* Bs,
                                               f32x4 (&acc)[4][4]) {
  const int tid = threadIdx.x, lane = tid & 63;
  const int wid = tid >> 6;
  const int wr = (wid >> 1) * 64, wc = (wid & 1) * 64;
  const int ar = tid >> 1, ak = (tid & 1) * 16;      // this thread's A span
  for (int k0 = 0; k0 < 1024; k0 += 32) {
    // B: async global->LDS (bf16 weights)
    #pragma unroll
    for (int it = 0; it < 2; ++it) {
      const int idx = tid * 8 + it * 2048;
      const int r = idx >> 5, kk = idx & 31;
      __builtin_amdgcn_global_load_lds(GLB_CAST(&Bt[(size_t)(n0 + r) * 1024 + k0 + kk]),
                                       LDS_CAST(&Bs[idx]), 16, 0, 0);
    }
    // A: reg-stage 16 f32 -> 16 bf16 -> LDS
    {
      const float4* src = reinterpret_cast<const float4*>(&A[(size_t)(m0 + ar) * 1024 + k0 + ak]);
      const float4 v0 = src[0], v1 = src[1], v2 = src[2], v3 = src[3];
      u16x8 lo, hi;
      lo[0] = f2b(v0.x); lo[1] = f2b(v0.y); lo[2] = f2b(v0.z); lo[3] = f2b(v0.w);
      lo[4] = f2b(v1.x); lo[5] = f2b(v1.y); lo[6] = f2b(v1.z); lo[7] = f2b(v1.w);
      hi[0] = f2b(v2.x); hi[1] = f2b(v2.y); hi[2] = f2b(v2.z); hi[3] = f2b(v2.w);
      hi[4] = f2b(v3.x); hi[5] = f2b(v3.y); hi[6] = f2b(v3.z); hi[7] = f2b(v3.w);
      *reinterpret_cast<u16x8*>(&As[ar * 32 + ak]) = lo;
      *reinterpret_cast<u16x8*>(&As[ar * 32 + ak + 8]) = hi;
    }
    __syncthreads();
    short8 af[4], bfv[4];
    #pragma unroll
    for (int m = 0; m < 4; ++m)
      af[m] = *reinterpret_cast<const short8*>(&As[(wr + m * 16 + (lane & 15)) * 32 + (lane >> 4) * 8]);
    #pragma unroll
    for (int n = 0; n < 4; ++n)
      bfv[n] = *reinterpret_cast<const short8*>(&Bs[(wc + n * 16 + (lane & 15)) * 32 + (lane >> 4) * 8]);
    #pragma unroll
    for (int m = 0; m < 4; ++m)
      #pragma unroll
      for (int n = 0; n < 4; ++n)
        acc[m][n] = __builtin_amdgcn_mfma_f32_16x16x32_bf16(af[m], bfv[n], acc[m][n], 0, 0, 0);
    __syncthreads();
  }
}

// QKV projections. z=0: Q, z=1: K -> (B,H,T,64); z=2: V -> TRANSPOSED (B,H,64,T)
__global__ __launch_bounds__(256) void gemm_proj(
    const float* __restrict__ qf, const float* __restrict__ kf, const float* __restrict__ vf,
    const ushort_t* __restrict__ Wqb, const ushort_t* __restrict__ Wvb,
    const float* __restrict__ bq, const float* __restrict__ bvv,
    ushort_t* __restrict__ Qh, ushort_t* __restrict__ Kh, ushort_t* __restrict__ Vt) {
  __shared__ ushort_t As[128 * 32], Bs[128 * 32];
  const float* A; const ushort_t* Bt; const float* bias;
  if (blockIdx.z == 0)      { A = qf; Bt = Wqb; bias = bq;  }
  else if (blockIdx.z == 1) { A = kf; Bt = Wqb; bias = bq;  }
  else                      { A = vf; Bt = Wvb; bias = bvv; }
  const int m0 = blockIdx.y * 128, n0 = blockIdx.x * 128;
  f32x4 zero = {0.f, 0.f, 0.f, 0.f};
  f32x4 acc[4][4];
  #pragma unroll
  for (int m = 0; m < 4; ++m)
    #pragma unroll
    for (int n = 0; n < 4; ++n) acc[m][n] = zero;
  gemm_core_f32A(A, Bt, m0, n0, As, Bs, acc);
  const int lane = threadIdx.x & 63, wid = threadIdx.x >> 6;
  const int wr = (wid >> 1) * 64, wc = (wid & 1) * 64;
  if (blockIdx.z == 2) {
    #pragma unroll
    for (int m = 0; m < 4; ++m)
      #pragma unroll
      for (int n = 0; n < 4; ++n) {
        const int rowb = m0 + wr + m * 16 + (lane >> 4) * 4;
        const int col  = n0 + wc + n * 16 + (lane & 15);
        u16x4 pk;
        #pragma unroll
        for (int r4 = 0; r4 < 4; ++r4) pk[r4] = f2b(acc[m][n][r4] + bias[col]);
        const int bi = rowb >> 10, t = rowb & 1023;
        *reinterpret_cast<u16x4*>(
            &Vt[((size_t)(bi * 16 + (col >> 6)) * 64 + (col & 63)) * 1024 + t]) = pk;
      }
  } else {
    ushort_t* dst = (blockIdx.z == 0) ? Qh : Kh;
    #pragma unroll
    for (int m = 0; m < 4; ++m)
      #pragma unroll
      for (int n = 0; n < 4; ++n)
        #pragma unroll
        for (int r4 = 0; r4 < 4; ++r4) {
          const int row = m0 + wr + m * 16 + (lane >> 4) * 4 + r4;
          const int col = n0 + wc + n * 16 + (lane & 15);
          const float v = acc[m][n][r4] + bias[col];
          const int bi = row >> 10, t = row & 1023, h = col >> 6, dd = col & 63;
          dst[((size_t)(bi * 16 + h) * 1024 + t) * 64 + dd] = f2b(v);
        }
  }
}

// ---------------------------------------------------------------------------
// bf16 GEMM core (both operands via global_load_lds) for gemm_out.
// ---------------------------------------------------------------------------
__device__ __forceinline__ void gemm_core(const ushort_t* __restrict__ A,
                                          const ushort_t* __restrict__ Bt,
                                          int m0, int n0,
                                          ushort_t* As, ushort_t* Bs,
                                          f32x4 (&acc)[4][4]) {
  const int tid = threadIdx.x, lane = tid & 63;
  const int wid = tid >> 6;
  const int wr = (wid >> 1) * 64, wc = (wid & 1) * 64;
  for (int k0 = 0; k0 < 1024; k0 += 32) {
    #pragma unroll
    for (int it = 0; it < 2; ++it) {
      const int idx = tid * 8 + it * 2048;
      const int r = idx >> 5, kk = idx & 31;
      __builtin_amdgcn_global_load_lds(GLB_CAST(&A[(size_t)(m0 + r) * 1024 + k0 + kk]),
                                       LDS_CAST(&As[idx]), 16, 0, 0);
      __builtin_amdgcn_global_load_lds(GLB_CAST(&Bt[(size_t)(n0 + r) * 1024 + k0 + kk]),
                                       LDS_CAST(&Bs[idx]), 16, 0, 0);
    }
    __syncthreads();
    short8 af[4], bfv[4];
    #pragma unroll
    for (int m = 0; m < 4; ++m)
      af[m] = *reinterpret_cast<const short8*>(&As[(wr + m * 16 + (lane & 15)) * 32 + (lane >> 4) * 8]);
    #pragma unroll
    for (int n = 0; n < 4; ++n)
      bfv[n] = *reinterpret_cast<const short8*>(&Bs[(wc + n * 16 + (lane & 15)) * 32 + (lane >> 4) * 8]);
    #pragma unroll
    for (int m = 0; m < 4; ++m)
      #pragma unroll
      for (int n = 0; n < 4; ++n)
        acc[m][n] = __builtin_amdgcn_mfma_f32_16x16x32_bf16(af[m], bfv[n], acc[m][n], 0, 0, 0);
    __syncthreads();
  }
}

// Output projection: x = concat@Wo^T + bo + query   (f32)
__global__ __launch_bounds__(256) void gemm_out(
    const ushort_t* __restrict__ A, const ushort_t* __restrict__ Bt,
    const float* __restrict__ bias, const float* __restrict__ resid,
    float* __restrict__ dstF) {
  __shared__ ushort_t As[128 * 32], Bs[128 * 32];
  const int m0 = blockIdx.y * 128, n0 = blockIdx.x * 128;
  f32x4 zero = {0.f, 0.f, 0.f, 0.f};
  f32x4 acc[4][4];
  #pragma unroll
  for (int m = 0; m < 4; ++m)
    #pragma unroll
    for (int n = 0; n < 4; ++n) acc[m][n] = zero;
  gemm_core(A, Bt, m0, n0, As, Bs, acc);
  const int lane = threadIdx.x & 63, wid = threadIdx.x >> 6;
  const int wr = (wid >> 1) * 64, wc = (wid & 1) * 64;
  #pragma unroll
  for (int m = 0; m < 4; ++m)
    #pragma unroll
    for (int n = 0; n < 4; ++n)
      #pragma unroll
      for (int r4 = 0; r4 < 4; ++r4) {
        const int row = m0 + wr + m * 16 + (lane >> 4) * 4 + r4;
        const int col = n0 + wc + n * 16 + (lane & 15);
        const size_t o = (size_t)row * 1024 + col;
        dstF[o] = acc[m][n][r4] + bias[col] + resid[o];
      }
}

// ---------------------------------------------------------------------------
// Width-adaptive aligned LDS row access for Phase B.
// ---------------------------------------------------------------------------
template<int CH>
__device__ __forceinline__ void load_row(const ushort_t* __restrict__ Row, float (&s)[CH]) {
  constexpr int W = (CH % 8 == 0) ? 8 : (CH % 4 == 0) ? 4 : (CH % 2 == 0) ? 2 : 1;
  #pragma unroll
  for (int b = 0; b < CH / W; ++b) {
    if constexpr (W == 8) {
      const u16x8 t = *reinterpret_cast<const u16x8*>(&Row[b * 8]);
      #pragma unroll
      for (int e = 0; e < 8; ++e) s[b * 8 + e] = b2f(t[e]);
    } else if constexpr (W == 4) {
      const u16x4 t = *reinterpret_cast<const u16x4*>(&Row[b * 4]);
      #pragma unroll
      for (int e = 0; e < 4; ++e) s[b * 4 + e] = b2f(t[e]);
    } else if constexpr (W == 2) {
      const u16x2 t = *reinterpret_cast<const u16x2*>(&Row[b * 2]);
      s[b * 2] = b2f(t[0]); s[b * 2 + 1] = b2f(t[1]);
    } else {
      s[b] = b2f(Row[b]);
    }
  }
}

template<int CH>
__device__ __forceinline__ void store_row(ushort_t* __restrict__ Row,
                                          const float (&p)[CH], const float sc) {
  constexpr int W = (CH % 8 == 0) ? 8 : (CH % 4 == 0) ? 4 : (CH % 2 == 0) ? 2 : 1;
  #pragma unroll
  for (int b = 0; b < CH / W; ++b) {
    if constexpr (W == 8) {
      u16x8 o;
      #pragma unroll
      for (int e = 0; e < 8; ++e) o[e] = f2b(p[b * 8 + e] * sc);
      *reinterpret_cast<u16x8*>(&Row[b * 8]) = o;
    } else if constexpr (W == 4) {
      u16x4 o;
      #pragma unroll
      for (int e = 0; e < 4; ++e) o[e] = f2b(p[b * 4 + e] * sc);
      *reinterpret_cast<u16x4*>(&Row[b * 4]) = o;
    } else if constexpr (W == 2) {
      u16x2 o;
      o[0] = f2b(p[b * 2] * sc); o[1] = f2b(p[b * 2 + 1] * sc);
      *reinterpret_cast<u16x2*>(&Row[b * 2]) = o;
    } else {
      Row[b] = f2b(p[b] * sc);
    }
  }
}

// ---------------------------------------------------------------------------
// Phase B worker, CH columns per lane.  4 waves x 4 rows = 16 rows.
// ---------------------------------------------------------------------------
template<int CH>
__device__ __forceinline__ void phase_b(ushort_t* __restrict__ Sb, const int i0,
                                        const int w, const int lane, const float gamx) {
  const int c0 = CH * lane;
  for (int rr = 0; rr < 4; ++rr) {
    const int r = w * 4 + rr;
    const int i = i0 + r;
    ushort_t* __restrict__ Row = &Sb[r * 1032 + c0];
    if (i == 0) {                       // fully masked row -> P = 0
      #pragma unroll
      for (int e = 0; e < CH; ++e) Row[e] = 0;
      continue;
    }
    const int nact = min(max(i - c0, 0), CH);
    float s[CH], ev[CH];
    load_row<CH>(Row, s);
    // mask + first exp (no max-sub; scores are O(1)) + in-lane total
    float run = 0.f;
    #pragma unroll
    for (int e = 0; e < CH; ++e) {
      s[e] = (e < nact) ? s[e] * LOG2E : -__builtin_inff();
      ev[e] = EXP2F(s[e]);              // exact 0 for masked
      run += ev[e];
    }
    // wave-level inclusive suffix of lane totals -> Z1, exclusive tail
    float v = run;
    #pragma unroll
    for (int d = 1; d < 64; d <<= 1) {
      const float t = __shfl_down(v, d);
      v += (lane + d < 64) ? t : 0.f;
    }
    const float Z1 = __shfl(v, 0);
    float run2 = v - run;               // tail beyond this lane's span
    // gamma effect + second exp + fused z2/mm accumulation (single pass)
    const float g2 = -gamx * rsqrtf(Z1);
    const float posb = (float)(i - c0);
    float z2 = 0.f, mm = 0.f;
    #pragma unroll
    for (int e = CH - 1; e >= 0; --e) {
      const float t = fmaxf(run2 * (posb - (float)e), 0.f);
      run2 += ev[e];
      const float eff = fmaxf(EXP2F(g2 * sqrtf(t)), 1e-5f);
      const float p = EXP2F(s[e] * eff);   // -inf stays -inf -> p = 0
      ev[e] = p;
      z2 += p;
      mm = fmaxf(mm, p);
    }
    #pragma unroll
    for (int d = 32; d > 0; d >>= 1) {
      z2 += __shfl_xor(z2, d);
      mm = fmaxf(mm, __shfl_xor(mm, d));
    }
    const float sc = fminf(1.f / mm, 5.f / z2);   // maxout-combined normalizer
    store_row<CH>(Row, ev, sc);
  }
}

// ---------------------------------------------------------------------------
// Attention (R7 config).  grid = (64,64) remapped: one bh-octet per XCD,
// heaviest i0 first.  256 threads (4 waves).  S plain [16][1032] bf16.
// ---------------------------------------------------------------------------
__global__ __launch_bounds__(256, 4) void attn_kernel(
    const ushort_t* __restrict__ Qh, const ushort_t* __restrict__ Kh,
    const ushort_t* __restrict__ Vt, const float* __restrict__ gammas,
    ushort_t* __restrict__ concat) {
  __shared__ __align__(16) ushort_t Sb[16 * 1032];
  __shared__ __align__(16) ushort_t Qs[16 * 72];     // padded stride 72
  const int tid = threadIdx.x, lane = tid & 63, w = tid >> 6;
  const int flat = blockIdx.x + (blockIdx.y << 6);
  const int bh = ((flat & 7) << 3) | (flat >> 9);
  const int i0 = (63 - ((flat >> 3) & 63)) << 4;     // heaviest first
  const int bi = bh >> 4, h = bh & 15;
  const size_t base = (size_t)bh * (1024 * 64);

  { // stage Q tile (16 rows x 64)
    const int r = tid >> 4, d = (tid & 15) * 4;
    *reinterpret_cast<u16x4*>(&Qs[r * 72 + d]) =
        *reinterpret_cast<const u16x4*>(&Qh[base + (size_t)(i0 + r) * 64 + d]);
  }
  __syncthreads();

  // ---- Phase A: scores -> bf16 S ----
  const int upper = i0 + 16;
  for (int nt = 0; nt < 16; ++nt) {
    const int colbase = (nt * 4 + w) * 16;
    if (colbase >= upper) break;
    f32x4 acc = {0.f, 0.f, 0.f, 0.f};
    #pragma unroll
    for (int kt = 0; kt < 2; ++kt) {
      const short8 a = *reinterpret_cast<const short8*>(
          &Qs[(lane & 15) * 72 + kt * 32 + (lane >> 4) * 8]);
      const short8 bb = *reinterpret_cast<const short8*>(
          &Kh[base + (size_t)(colbase + (lane & 15)) * 64 + kt * 32 + (lane >> 4) * 8]);
      acc = __builtin_amdgcn_mfma_f32_16x16x32_bf16(a, bb, acc, 0, 0, 0);
    }
    const int j = colbase + (lane & 15);
    #pragma unroll
    for (int r4 = 0; r4 < 4; ++r4) {
      const int rf = (lane >> 4) * 4 + r4;
      Sb[rf * 1032 + j] = f2b(acc[r4] * 0.125f);
    }
  }
  __syncthreads();

  // ---- Phase B: exact-even causal tiering, 4 rows/wave ----
  const float gamx = fabsf(gammas[h]) * LOG2E;
  const int chp = (upper + 63) >> 6;        // col-blocks needed (block-uniform)
  switch (chp) {
    case 1:           phase_b<1 >(Sb, i0, w, lane, gamx); break;
    case 2:           phase_b<2 >(Sb, i0, w, lane, gamx); break;
    case 3: case 4:   phase_b<4 >(Sb, i0, w, lane, gamx); break;
    case 5: case 6:   phase_b<6 >(Sb, i0, w, lane, gamx); break;
    case 7: case 8:   phase_b<8 >(Sb, i0, w, lane, gamx); break;
    case 9: case 10:  phase_b<10>(Sb, i0, w, lane, gamx); break;
    case 11: case 12: phase_b<12>(Sb, i0, w, lane, gamx); break;
    case 13: case 14: phase_b<14>(Sb, i0, w, lane, gamx); break;
    default:          phase_b<16>(Sb, i0, w, lane, gamx); break;
  }
  __syncthreads();

  // ---- Phase C: PV via MFMA.  wave w -> d-tile d0 = w*16 ----
  {
    const int d0 = w * 16;
    const int arow = lane & 15;
    const ushort_t* Prow = &Sb[arow * 1032];
    const ushort_t* Vrow = Vt + base + (size_t)(d0 + arow) * 1024;
    const int kmax = (upper + 31) & ~31;
    f32x4 acc = {0.f, 0.f, 0.f, 0.f};
    for (int k0 = 0; k0 < kmax; k0 += 32) {
      const short8 a = *reinterpret_cast<const short8*>(&Prow[k0 + (lane >> 4) * 8]);
      const short8 bb = *reinterpret_cast<const short8*>(&Vrow[k0 + (lane >> 4) * 8]);
      acc = __builtin_amdgcn_mfma_f32_16x16x32_bf16(a, bb, acc, 0, 0, 0);
    }
    #pragma unroll
    for (int r4 = 0; r4 < 4; ++r4) {
      const int row = (lane >> 4) * 4 + r4;
      const int i = i0 + row;
      concat[((size_t)(bi * 1024 + i)) * 1024 + h * 64 + d0 + arow] = f2b(acc[r4]);
    }
  }
}

// ---------------------------------------------------------------------------
__global__ __launch_bounds__(256) void ln_kernel(const float* __restrict__ x,
                                                 const float* __restrict__ g,
                                                 const float* __restrict__ bb,
                                                 float* __restrict__ out) {
  const int row = blockIdx.x, tid = threadIdx.x, lane = tid & 63, w = tid >> 6;
  const float4 v = reinterpret_cast<const float4*>(x + (size_t)row * 1024)[tid];
  float s = v.x + v.y + v.z + v.w;
  float q = v.x * v.x + v.y * v.y + v.z * v.z + v.w * v.w;
  s = wave_sum(s); q = wave_sum(q);
  __shared__ float ps[4], pq[4];
  if (lane == 0) { ps[w] = s; pq[w] = q; }
  __syncthreads();
  const float ts = ps[0] + ps[1] + ps[2] + ps[3];
  const float tq = pq[0] + pq[1] + pq[2] + pq[3];
  const float mu = ts * (1.f / 1024.f);
  const float inv = rsqrtf(tq * (1.f / 1024.f) - mu * mu + 1e-5f);
  const float4 gv = reinterpret_cast<const float4*>(g)[tid];
  const float4 bv = reinterpret_cast<const float4*>(bb)[tid];
  float4 o;
  o.x = (v.x - mu) * inv * gv.x + bv.x;
  o.y = (v.y - mu) * inv * gv.y + bv.y;
  o.z = (v.z - mu) * inv * gv.z + bv.z;
  o.w = (v.w - mu) * inv * gv.w + bv.w;
  reinterpret_cast<float4*>(out + (size_t)row * 1024)[tid] = o;
}

// ---------------------------------------------------------------------------
extern "C" void kernel_launch(void* const* d_in, const int* in_sizes, int n_in,
                              void* d_out, int out_size, void* d_ws, size_t ws_size,
                              hipStream_t stream) {
  (void)in_sizes; (void)n_in; (void)out_size; (void)ws_size;
  const float* query  = (const float*)d_in[0];
  const float* key    = (const float*)d_in[1];
  const float* values = (const float*)d_in[2];
  const float* Wq     = (const float*)d_in[3];
  const float* bq     = (const float*)d_in[4];
  const float* Wv     = (const float*)d_in[5];
  const float* bv     = (const float*)d_in[6];
  const float* Wo     = (const float*)d_in[7];
  const float* bo     = (const float*)d_in[8];
  const float* gammas = (const float*)d_in[9];
  const float* ln_g   = (const float*)d_in[10];
  const float* ln_b   = (const float*)d_in[11];
  float* out = (float*)d_out;

  const size_t NT = 4096ull * 1024;     // token elements
  const size_t NW = 1024ull * 1024;     // weight elements
  char* p = (char*)d_ws;
  ushort_t* Wqb    = (ushort_t*)p; p += NW * 2;
  ushort_t* Wvb    = (ushort_t*)p; p += NW * 2;
  ushort_t* Wob    = (ushort_t*)p; p += NW * 2;
  ushort_t* Qh     = (ushort_t*)p; p += NT * 2;
  ushort_t* Kh     = (ushort_t*)p; p += NT * 2;
  ushort_t* Vt     = (ushort_t*)p; p += NT * 2;
  ushort_t* concat = (ushort_t*)p; p += NT * 2;
  float*    xbuf   = (float*)p;    p += NT * 4;

  conv3_f32_bf16<<<dim3(1024, 3), 256, 0, stream>>>(Wq, Wv, Wo, Wqb, Wvb, Wob, (int)(NW / 4));

  gemm_proj<<<dim3(8, 32, 3), 256, 0, stream>>>(query, key, values, Wqb, Wvb, bq, bv, Qh, Kh, Vt);
  attn_kernel<<<dim3(64, 64), 256, 0, stream>>>(Qh, Kh, Vt, gammas, concat);
  gemm_out<<<dim3(8, 32), 256, 0, stream>>>(concat, Wob, bo, query, xbuf);
  ln_kernel<<<4096, 256, 0, stream>>>(xbuf, ln_g, ln_b, out);
}

// Round 13
// 173.062 us; speedup vs baseline: 1.0940x; 1.0940x over previous
//
#include <hip/hip_runtime.h>
#include <hip/hip_bf16.h>
#include <stdint.h>

// ---------------------------------------------------------------------------
// DTransformer layer on MI355X.  B=4, T=1024, D=1024, H=16, dk=64.
//   1. conv f32 -> bf16 (single batched launch, tokens + weights)
//   2. gemm_proj (128x128, z-grid): Q,K (B,H,T,64), V -> transposed (B,H,64,T)
//   3. attn (R7 config: 256 thr, 4 waves, 16-row blocks, XCD swizzle,
//      heaviest-first, exact-even-tiered no-max-sub softmax; scores stored
//      pre-scaled by 0.125*LOG2E so Phase B runs raw exp2)
//   4. gemm_out: x = concat@Wo^T + bo + query   5. layernorm
// ---------------------------------------------------------------------------

typedef unsigned short ushort_t;
typedef __attribute__((ext_vector_type(8))) short short8;
typedef __attribute__((ext_vector_type(8))) unsigned short u16x8;
typedef __attribute__((ext_vector_type(4))) float f32x4;
typedef __attribute__((ext_vector_type(4))) unsigned short u16x4;
typedef __attribute__((ext_vector_type(2))) unsigned short u16x2;

#define GLB_CAST(p) ((const __attribute__((address_space(1))) void*)(p))
#define LDS_CAST(p) ((__attribute__((address_space(3))) void*)(p))

#if __has_builtin(__builtin_amdgcn_exp2f)
#define EXP2F(x) __builtin_amdgcn_exp2f(x)
#else
#define EXP2F(x) exp2f(x)
#endif

#define LOG2E 1.44269504f

__device__ __forceinline__ float b2f(ushort_t u) {
  union { unsigned int i; float f; } x; x.i = ((unsigned int)u) << 16; return x.f;
}
__device__ __forceinline__ ushort_t f2b(float f) {   // RNE via hw convert
  __hip_bfloat16 h = __float2bfloat16(f);
  return *reinterpret_cast<ushort_t*>(&h);
}
__device__ __forceinline__ float wave_sum(float v) {
  #pragma unroll
  for (int d = 32; d > 0; d >>= 1) v += __shfl_xor(v, d);
  return v;
}

// ---------------------------------------------------------------------------
// batched f32 -> bf16 converts: y 0..2 tokens (4096 blk), y 3..5 weights (1024)
// ---------------------------------------------------------------------------
__global__ void conv6_f32_bf16(const float* __restrict__ s0, const float* __restrict__ s1,
                               const float* __restrict__ s2, const float* __restrict__ s3,
                               const float* __restrict__ s4, const float* __restrict__ s5,
                               ushort_t* __restrict__ d0, ushort_t* __restrict__ d1,
                               ushort_t* __restrict__ d2, ushort_t* __restrict__ d3,
                               ushort_t* __restrict__ d4, ushort_t* __restrict__ d5,
                               int n4tok, int n4w) {
  const int y = blockIdx.y;
  const float* srcs[6] = {s0, s1, s2, s3, s4, s5};
  ushort_t*    dsts[6] = {d0, d1, d2, d3, d4, d5};
  const int n4 = (y < 3) ? n4tok : n4w;
  int i = blockIdx.x * blockDim.x + threadIdx.x;
  if (i < n4) {
    const float4 v = reinterpret_cast<const float4*>(srcs[y])[i];
    u16x4 o;
    o[0] = f2b(v.x); o[1] = f2b(v.y); o[2] = f2b(v.z); o[3] = f2b(v.w);
    reinterpret_cast<u16x4*>(dsts[y])[i] = o;
  }
}

// ---------------------------------------------------------------------------
// 128x128 tile bf16 GEMM core: C[m,n] = sum_k A[m,k]*Bt[n,k]
// ---------------------------------------------------------------------------
__device__ __forceinline__ void gemm_core(const ushort_t* __restrict__ A,
                                          const ushort_t* __restrict__ Bt,
                                          int m0, int n0,
                                          ushort_t* As, ushort_t* Bs,
                                          f32x4 (&acc)[4][4]) {
  const int tid = threadIdx.x, lane = tid & 63;
  const int wid = tid >> 6;
  const int wr = (wid >> 1) * 64, wc = (wid & 1) * 64;
  for (int k0 = 0; k0 < 1024; k0 += 32) {
    #pragma unroll
    for (int it = 0; it < 2; ++it) {
      const int idx = tid * 8 + it * 2048;
      const int r = idx >> 5, kk = idx & 31;
      __builtin_amdgcn_global_load_lds(GLB_CAST(&A[(size_t)(m0 + r) * 1024 + k0 + kk]),
                                       LDS_CAST(&As[idx]), 16, 0, 0);
      __builtin_amdgcn_global_load_lds(GLB_CAST(&Bt[(size_t)(n0 + r) * 1024 + k0 + kk]),
                                       LDS_CAST(&Bs[idx]), 16, 0, 0);
    }
    __syncthreads();
    short8 af[4], bfv[4];
    #pragma unroll
    for (int m = 0; m < 4; ++m)
      af[m] = *reinterpret_cast<const short8*>(&As[(wr + m * 16 + (lane & 15)) * 32 + (lane >> 4) * 8]);
    #pragma unroll
    for (int n = 0; n < 4; ++n)
      bfv[n] = *reinterpret_cast<const short8*>(&Bs[(wc + n * 16 + (lane & 15)) * 32 + (lane >> 4) * 8]);
    #pragma unroll
    for (int m = 0; m < 4; ++m)
      #pragma unroll
      for (int n = 0; n < 4; ++n)
        acc[m][n] = __builtin_amdgcn_mfma_f32_16x16x32_bf16(af[m], bfv[n], acc[m][n], 0, 0, 0);
    __syncthreads();
  }
}

// QKV projections. z=0: Q, z=1: K -> (B,H,T,64); z=2: V -> TRANSPOSED (B,H,64,T)
__global__ __launch_bounds__(256) void gemm_proj(
    const ushort_t* __restrict__ qb, const ushort_t* __restrict__ kb, const ushort_t* __restrict__ vb,
    const ushort_t* __restrict__ Wqb, const ushort_t* __restrict__ Wvb,
    const float* __restrict__ bq, const float* __restrict__ bvv,
    ushort_t* __restrict__ Qh, ushort_t* __restrict__ Kh, ushort_t* __restrict__ Vt) {
  __shared__ ushort_t As[128 * 32], Bs[128 * 32];
  const ushort_t* A; const ushort_t* Bt; const float* bias;
  if (blockIdx.z == 0)      { A = qb; Bt = Wqb; bias = bq;  }
  else if (blockIdx.z == 1) { A = kb; Bt = Wqb; bias = bq;  }
  else                      { A = vb; Bt = Wvb; bias = bvv; }
  const int m0 = blockIdx.y * 128, n0 = blockIdx.x * 128;
  f32x4 zero = {0.f, 0.f, 0.f, 0.f};
  f32x4 acc[4][4];
  #pragma unroll
  for (int m = 0; m < 4; ++m)
    #pragma unroll
    for (int n = 0; n < 4; ++n) acc[m][n] = zero;
  gemm_core(A, Bt, m0, n0, As, Bs, acc);
  const int lane = threadIdx.x & 63, wid = threadIdx.x >> 6;
  const int wr = (wid >> 1) * 64, wc = (wid & 1) * 64;
  if (blockIdx.z == 2) {
    #pragma unroll
    for (int m = 0; m < 4; ++m)
      #pragma unroll
      for (int n = 0; n < 4; ++n) {
        const int rowb = m0 + wr + m * 16 + (lane >> 4) * 4;
        const int col  = n0 + wc + n * 16 + (lane & 15);
        u16x4 pk;
        #pragma unroll
        for (int r4 = 0; r4 < 4; ++r4) pk[r4] = f2b(acc[m][n][r4] + bias[col]);
        const int bi = rowb >> 10, t = rowb & 1023;
        *reinterpret_cast<u16x4*>(
            &Vt[((size_t)(bi * 16 + (col >> 6)) * 64 + (col & 63)) * 1024 + t]) = pk;
      }
  } else {
    ushort_t* dst = (blockIdx.z == 0) ? Qh : Kh;
    #pragma unroll
    for (int m = 0; m < 4; ++m)
      #pragma unroll
      for (int n = 0; n < 4; ++n)
        #pragma unroll
        for (int r4 = 0; r4 < 4; ++r4) {
          const int row = m0 + wr + m * 16 + (lane >> 4) * 4 + r4;
          const int col = n0 + wc + n * 16 + (lane & 15);
          const float v = acc[m][n][r4] + bias[col];
          const int bi = row >> 10, t = row & 1023, h = col >> 6, dd = col & 63;
          dst[((size_t)(bi * 16 + h) * 1024 + t) * 64 + dd] = f2b(v);
        }
  }
}

// Output projection: x = concat@Wo^T + bo + query   (f32)
__global__ __launch_bounds__(256) void gemm_out(
    const ushort_t* __restrict__ A, const ushort_t* __restrict__ Bt,
    const float* __restrict__ bias, const float* __restrict__ resid,
    float* __restrict__ dstF) {
  __shared__ ushort_t As[128 * 32], Bs[128 * 32];
  const int m0 = blockIdx.y * 128, n0 = blockIdx.x * 128;
  f32x4 zero = {0.f, 0.f, 0.f, 0.f};
  f32x4 acc[4][4];
  #pragma unroll
  for (int m = 0; m < 4; ++m)
    #pragma unroll
    for (int n = 0; n < 4; ++n) acc[m][n] = zero;
  gemm_core(A, Bt, m0, n0, As, Bs, acc);
  const int lane = threadIdx.x & 63, wid = threadIdx.x >> 6;
  const int wr = (wid >> 1) * 64, wc = (wid & 1) * 64;
  #pragma unroll
  for (int m = 0; m < 4; ++m)
    #pragma unroll
    for (int n = 0; n < 4; ++n)
      #pragma unroll
      for (int r4 = 0; r4 < 4; ++r4) {
        const int row = m0 + wr + m * 16 + (lane >> 4) * 4 + r4;
        const int col = n0 + wc + n * 16 + (lane & 15);
        const size_t o = (size_t)row * 1024 + col;
        dstF[o] = acc[m][n][r4] + bias[col] + resid[o];
      }
}

// ---------------------------------------------------------------------------
// Width-adaptive aligned LDS row access for Phase B.
// ---------------------------------------------------------------------------
template<int CH>
__device__ __forceinline__ void load_row(const ushort_t* __restrict__ Row, float (&s)[CH]) {
  constexpr int W = (CH % 8 == 0) ? 8 : (CH % 4 == 0) ? 4 : (CH % 2 == 0) ? 2 : 1;
  #pragma unroll
  for (int b = 0; b < CH / W; ++b) {
    if constexpr (W == 8) {
      const u16x8 t = *reinterpret_cast<const u16x8*>(&Row[b * 8]);
      #pragma unroll
      for (int e = 0; e < 8; ++e) s[b * 8 + e] = b2f(t[e]);
    } else if constexpr (W == 4) {
      const u16x4 t = *reinterpret_cast<const u16x4*>(&Row[b * 4]);
      #pragma unroll
      for (int e = 0; e < 4; ++e) s[b * 4 + e] = b2f(t[e]);
    } else if constexpr (W == 2) {
      const u16x2 t = *reinterpret_cast<const u16x2*>(&Row[b * 2]);
      s[b * 2] = b2f(t[0]); s[b * 2 + 1] = b2f(t[1]);
    } else {
      s[b] = b2f(Row[b]);
    }
  }
}

template<int CH>
__device__ __forceinline__ void store_row(ushort_t* __restrict__ Row,
                                          const float (&p)[CH], const float sc) {
  constexpr int W = (CH % 8 == 0) ? 8 : (CH % 4 == 0) ? 4 : (CH % 2 == 0) ? 2 : 1;
  #pragma unroll
  for (int b = 0; b < CH / W; ++b) {
    if constexpr (W == 8) {
      u16x8 o;
      #pragma unroll
      for (int e = 0; e < 8; ++e) o[e] = f2b(p[b * 8 + e] * sc);
      *reinterpret_cast<u16x8*>(&Row[b * 8]) = o;
    } else if constexpr (W == 4) {
      u16x4 o;
      #pragma unroll
      for (int e = 0; e < 4; ++e) o[e] = f2b(p[b * 4 + e] * sc);
      *reinterpret_cast<u16x4*>(&Row[b * 4]) = o;
    } else if constexpr (W == 2) {
      u16x2 o;
      o[0] = f2b(p[b * 2] * sc); o[1] = f2b(p[b * 2 + 1] * sc);
      *reinterpret_cast<u16x2*>(&Row[b * 2]) = o;
    } else {
      Row[b] = f2b(p[b] * sc);
    }
  }
}

// ---------------------------------------------------------------------------
// Phase B worker, CH columns per lane.  4 waves x 4 rows = 16 rows.
// Scores in LDS are pre-scaled by LOG2E (raw exp2 domain).
// ---------------------------------------------------------------------------
template<int CH>
__device__ __forceinline__ void phase_b(ushort_t* __restrict__ Sb, const int i0,
                                        const int w, const int lane, const float gamx) {
  const int c0 = CH * lane;
  for (int rr = 0; rr < 4; ++rr) {
    const int r = w * 4 + rr;
    const int i = i0 + r;
    ushort_t* __restrict__ Row = &Sb[r * 1032 + c0];
    if (i == 0) {                       // fully masked row -> P = 0
      #pragma unroll
      for (int e = 0; e < CH; ++e) Row[e] = 0;
      continue;
    }
    const int nact = min(max(i - c0, 0), CH);
    float s[CH], ev[CH];
    load_row<CH>(Row, s);
    // mask + first exp (no max-sub; scores are O(1)) + in-lane total
    float run = 0.f;
    #pragma unroll
    for (int e = 0; e < CH; ++e) {
      s[e] = (e < nact) ? s[e] : -__builtin_inff();
      ev[e] = EXP2F(s[e]);              // exact 0 for masked
      run += ev[e];
    }
    // wave-level inclusive suffix of lane totals -> Z1, exclusive tail
    float v = run;
    #pragma unroll
    for (int d = 1; d < 64; d <<= 1) {
      const float t = __shfl_down(v, d);
      v += (lane + d < 64) ? t : 0.f;
    }
    const float Z1 = __shfl(v, 0);
    float run2 = v - run;               // tail beyond this lane's span
    // gamma effect + second exp + fused z2/mm accumulation (single pass)
    const float g2 = -gamx * rsqrtf(Z1);
    const float posb = (float)(i - c0);
    float z2 = 0.f, mm = 0.f;
    #pragma unroll
    for (int e = CH - 1; e >= 0; --e) {
      const float t = fmaxf(run2 * (posb - (float)e), 0.f);
      run2 += ev[e];
      const float eff = fmaxf(EXP2F(g2 * sqrtf(t)), 1e-5f);
      const float p = EXP2F(s[e] * eff);   // -inf stays -inf -> p = 0
      ev[e] = p;
      z2 += p;
      mm = fmaxf(mm, p);
    }
    #pragma unroll
    for (int d = 32; d > 0; d >>= 1) {
      z2 += __shfl_xor(z2, d);
      mm = fmaxf(mm, __shfl_xor(mm, d));
    }
    const float sc = fminf(1.f / mm, 5.f / z2);   // maxout-combined normalizer
    store_row<CH>(Row, ev, sc);
  }
}

// ---------------------------------------------------------------------------
// Attention (R7 config).  grid = (64,64) remapped: one bh-octet per XCD,
// heaviest i0 first.  256 threads (4 waves).  S plain [16][1032] bf16.
// ---------------------------------------------------------------------------
__global__ __launch_bounds__(256, 4) void attn_kernel(
    const ushort_t* __restrict__ Qh, const ushort_t* __restrict__ Kh,
    const ushort_t* __restrict__ Vt, const float* __restrict__ gammas,
    ushort_t* __restrict__ concat) {
  __shared__ __align__(16) ushort_t Sb[16 * 1032];
  __shared__ __align__(16) ushort_t Qs[16 * 72];     // padded stride 72
  const int tid = threadIdx.x, lane = tid & 63, w = tid >> 6;
  const int flat = blockIdx.x + (blockIdx.y << 6);
  const int bh = ((flat & 7) << 3) | (flat >> 9);
  const int i0 = (63 - ((flat >> 3) & 63)) << 4;     // heaviest first
  const int bi = bh >> 4, h = bh & 15;
  const size_t base = (size_t)bh * (1024 * 64);

  { // stage Q tile (16 rows x 64)
    const int r = tid >> 4, d = (tid & 15) * 4;
    *reinterpret_cast<u16x4*>(&Qs[r * 72 + d]) =
        *reinterpret_cast<const u16x4*>(&Qh[base + (size_t)(i0 + r) * 64 + d]);
  }
  __syncthreads();

  // ---- Phase A: scores * (0.125*LOG2E) -> bf16 S ----
  const int upper = i0 + 16;
  for (int nt = 0; nt < 16; ++nt) {
    const int colbase = (nt * 4 + w) * 16;
    if (colbase >= upper) break;
    f32x4 acc = {0.f, 0.f, 0.f, 0.f};
    #pragma unroll
    for (int kt = 0; kt < 2; ++kt) {
      const short8 a = *reinterpret_cast<const short8*>(
          &Qs[(lane & 15) * 72 + kt * 32 + (lane >> 4) * 8]);
      const short8 bb = *reinterpret_cast<const short8*>(
          &Kh[base + (size_t)(colbase + (lane & 15)) * 64 + kt * 32 + (lane >> 4) * 8]);
      acc = __builtin_amdgcn_mfma_f32_16x16x32_bf16(a, bb, acc, 0, 0, 0);
    }
    const int j = colbase + (lane & 15);
    #pragma unroll
    for (int r4 = 0; r4 < 4; ++r4) {
      const int rf = (lane >> 4) * 4 + r4;
      Sb[rf * 1032 + j] = f2b(acc[r4] * (0.125f * LOG2E));
    }
  }
  __syncthreads();

  // ---- Phase B: exact-even causal tiering, 4 rows/wave ----
  const float gamx = fabsf(gammas[h]) * LOG2E;
  const int chp = (upper + 63) >> 6;        // col-blocks needed (block-uniform)
  switch (chp) {
    case 1:           phase_b<1 >(Sb, i0, w, lane, gamx); break;
    case 2:           phase_b<2 >(Sb, i0, w, lane, gamx); break;
    case 3: case 4:   phase_b<4 >(Sb, i0, w, lane, gamx); break;
    case 5: case 6:   phase_b<6 >(Sb, i0, w, lane, gamx); break;
    case 7: case 8:   phase_b<8 >(Sb, i0, w, lane, gamx); break;
    case 9: case 10:  phase_b<10>(Sb, i0, w, lane, gamx); break;
    case 11: case 12: phase_b<12>(Sb, i0, w, lane, gamx); break;
    case 13: case 14: phase_b<14>(Sb, i0, w, lane, gamx); break;
    default:          phase_b<16>(Sb, i0, w, lane, gamx); break;
  }
  __syncthreads();

  // ---- Phase C: PV via MFMA.  wave w -> d-tile d0 = w*16 ----
  {
    const int d0 = w * 16;
    const int arow = lane & 15;
    const ushort_t* Prow = &Sb[arow * 1032];
    const ushort_t* Vrow = Vt + base + (size_t)(d0 + arow) * 1024;
    const int kmax = (upper + 31) & ~31;
    f32x4 acc = {0.f, 0.f, 0.f, 0.f};
    for (int k0 = 0; k0 < kmax; k0 += 32) {
      const short8 a = *reinterpret_cast<const short8*>(&Prow[k0 + (lane >> 4) * 8]);
      const short8 bb = *reinterpret_cast<const short8*>(&Vrow[k0 + (lane >> 4) * 8]);
      acc = __builtin_amdgcn_mfma_f32_16x16x32_bf16(a, bb, acc, 0, 0, 0);
    }
    #pragma unroll
    for (int r4 = 0; r4 < 4; ++r4) {
      const int row = (lane >> 4) * 4 + r4;
      const int i = i0 + row;
      concat[((size_t)(bi * 1024 + i)) * 1024 + h * 64 + d0 + arow] = f2b(acc[r4]);
    }
  }
}

// ---------------------------------------------------------------------------
__global__ __launch_bounds__(256) void ln_kernel(const float* __restrict__ x,
                                                 const float* __restrict__ g,
                                                 const float* __restrict__ bb,
                                                 float* __restrict__ out) {
  const int row = blockIdx.x, tid = threadIdx.x, lane = tid & 63, w = tid >> 6;
  const float4 v = reinterpret_cast<const float4*>(x + (size_t)row * 1024)[tid];
  float s = v.x + v.y + v.z + v.w;
  float q = v.x * v.x + v.y * v.y + v.z * v.z + v.w * v.w;
  s = wave_sum(s); q = wave_sum(q);
  __shared__ float ps[4], pq[4];
  if (lane == 0) { ps[w] = s; pq[w] = q; }
  __syncthreads();
  const float ts = ps[0] + ps[1] + ps[2] + ps[3];
  const float tq = pq[0] + pq[1] + pq[2] + pq[3];
  const float mu = ts * (1.f / 1024.f);
  const float inv = rsqrtf(tq * (1.f / 1024.f) - mu * mu + 1e-5f);
  const float4 gv = reinterpret_cast<const float4*>(g)[tid];
  const float4 bv = reinterpret_cast<const float4*>(bb)[tid];
  float4 o;
  o.x = (v.x - mu) * inv * gv.x + bv.x;
  o.y = (v.y - mu) * inv * gv.y + bv.y;
  o.z = (v.z - mu) * inv * gv.z + bv.z;
  o.w = (v.w - mu) * inv * gv.w + bv.w;
  reinterpret_cast<float4*>(out + (size_t)row * 1024)[tid] = o;
}

// ---------------------------------------------------------------------------
extern "C" void kernel_launch(void* const* d_in, const int* in_sizes, int n_in,
                              void* d_out, int out_size, void* d_ws, size_t ws_size,
                              hipStream_t stream) {
  (void)in_sizes; (void)n_in; (void)out_size; (void)ws_size;
  const float* query  = (const float*)d_in[0];
  const float* key    = (const float*)d_in[1];
  const float* values = (const float*)d_in[2];
  const float* Wq     = (const float*)d_in[3];
  const float* bq     = (const float*)d_in[4];
  const float* Wv     = (const float*)d_in[5];
  const float* bv     = (const float*)d_in[6];
  const float* Wo     = (const float*)d_in[7];
  const float* bo     = (const float*)d_in[8];
  const float* gammas = (const float*)d_in[9];
  const float* ln_g   = (const float*)d_in[10];
  const float* ln_b   = (const float*)d_in[11];
  float* out = (float*)d_out;

  const size_t NT = 4096ull * 1024;
  const size_t NW = 1024ull * 1024;
  char* p = (char*)d_ws;
  ushort_t* qb  = (ushort_t*)p; p += NT * 2;
  ushort_t* kb  = (ushort_t*)p; p += NT * 2;
  ushort_t* vb  = (ushort_t*)p; p += NT * 2;
  ushort_t* Wqb = (ushort_t*)p; p += NW * 2;
  ushort_t* Wvb = (ushort_t*)p; p += NW * 2;
  ushort_t* Wob = (ushort_t*)p; p += NW * 2;
  ushort_t* Qh  = (ushort_t*)p; p += NT * 2;
  ushort_t* Kh  = (ushort_t*)p; p += NT * 2;
  ushort_t* Vt  = (ushort_t*)p; p += NT * 2;
  ushort_t* concat = vb;                // free after gemm_proj
  float*    xbuf   = (float*)qb;        // spans qb+kb, free after gemm_proj

  conv6_f32_bf16<<<dim3(4096, 6), 256, 0, stream>>>(
      query, key, values, Wq, Wv, Wo, qb, kb, vb, Wqb, Wvb, Wob,
      (int)(NT / 4), (int)(NW / 4));

  gemm_proj<<<dim3(8, 32, 3), 256, 0, stream>>>(qb, kb, vb, Wqb, Wvb, bq, bv, Qh, Kh, Vt);
  attn_kernel<<<dim3(64, 64), 256, 0, stream>>>(Qh, Kh, Vt, gammas, concat);
  gemm_out<<<dim3(8, 32), 256, 0, stream>>>(concat, Wob, bo, query, xbuf);
  ln_kernel<<<4096, 256, 0, stream>>>(xbuf, ln_g, ln_b, out);
}

// Round 14
// 171.571 us; speedup vs baseline: 1.1035x; 1.0087x over previous
//
#include <hip/hip_runtime.h>
#include <hip/hip_bf16.h>
#include <stdint.h>

// ---------------------------------------------------------------------------
// DTransformer layer on MI355X.  B=4, T=1024, D=1024, H=16, dk=64.
//   1. conv f32 -> bf16 (single batched launch, tokens + weights)
//   2. gemm_proj (128x128, z-grid): Q,K (B,H,T,64), V -> transposed (B,H,64,T)
//   3. attn (R7 config: 256 thr, 4 waves, 16-row blocks, XCD swizzle,
//      heaviest-first, exact-even-tiered no-max-sub softmax, exp2 domain)
//   4. gemm_out: x = concat@Wo^T + bo + query  -> bf16 xbuf (residual is O(1))
//   5. layernorm (bf16 in, f32 out)
// ---------------------------------------------------------------------------

typedef unsigned short ushort_t;
typedef __attribute__((ext_vector_type(8))) short short8;
typedef __attribute__((ext_vector_type(8))) unsigned short u16x8;
typedef __attribute__((ext_vector_type(4))) float f32x4;
typedef __attribute__((ext_vector_type(4))) unsigned short u16x4;
typedef __attribute__((ext_vector_type(2))) unsigned short u16x2;

#define GLB_CAST(p) ((const __attribute__((address_space(1))) void*)(p))
#define LDS_CAST(p) ((__attribute__((address_space(3))) void*)(p))

#if __has_builtin(__builtin_amdgcn_exp2f)
#define EXP2F(x) __builtin_amdgcn_exp2f(x)
#else
#define EXP2F(x) exp2f(x)
#endif

#define LOG2E 1.44269504f

__device__ __forceinline__ float b2f(ushort_t u) {
  union { unsigned int i; float f; } x; x.i = ((unsigned int)u) << 16; return x.f;
}
__device__ __forceinline__ ushort_t f2b(float f) {   // RNE via hw convert
  __hip_bfloat16 h = __float2bfloat16(f);
  return *reinterpret_cast<ushort_t*>(&h);
}
__device__ __forceinline__ float wave_sum(float v) {
  #pragma unroll
  for (int d = 32; d > 0; d >>= 1) v += __shfl_xor(v, d);
  return v;
}

// ---------------------------------------------------------------------------
// batched f32 -> bf16 converts: y 0..2 tokens (4096 blk), y 3..5 weights (1024)
// ---------------------------------------------------------------------------
__global__ void conv6_f32_bf16(const float* __restrict__ s0, const float* __restrict__ s1,
                               const float* __restrict__ s2, const float* __restrict__ s3,
                               const float* __restrict__ s4, const float* __restrict__ s5,
                               ushort_t* __restrict__ d0, ushort_t* __restrict__ d1,
                               ushort_t* __restrict__ d2, ushort_t* __restrict__ d3,
                               ushort_t* __restrict__ d4, ushort_t* __restrict__ d5,
                               int n4tok, int n4w) {
  const int y = blockIdx.y;
  const float* srcs[6] = {s0, s1, s2, s3, s4, s5};
  ushort_t*    dsts[6] = {d0, d1, d2, d3, d4, d5};
  const int n4 = (y < 3) ? n4tok : n4w;
  int i = blockIdx.x * blockDim.x + threadIdx.x;
  if (i < n4) {
    const float4 v = reinterpret_cast<const float4*>(srcs[y])[i];
    u16x4 o;
    o[0] = f2b(v.x); o[1] = f2b(v.y); o[2] = f2b(v.z); o[3] = f2b(v.w);
    reinterpret_cast<u16x4*>(dsts[y])[i] = o;
  }
}

// ---------------------------------------------------------------------------
// 128x128 tile bf16 GEMM core: C[m,n] = sum_k A[m,k]*Bt[n,k]
// ---------------------------------------------------------------------------
__device__ __forceinline__ void gemm_core(const ushort_t* __restrict__ A,
                                          const ushort_t* __restrict__ Bt,
                                          int m0, int n0,
                                          ushort_t* As, ushort_t* Bs,
                                          f32x4 (&acc)[4][4]) {
  const int tid = threadIdx.x, lane = tid & 63;
  const int wid = tid >> 6;
  const int wr = (wid >> 1) * 64, wc = (wid & 1) * 64;
  for (int k0 = 0; k0 < 1024; k0 += 32) {
    #pragma unroll
    for (int it = 0; it < 2; ++it) {
      const int idx = tid * 8 + it * 2048;
      const int r = idx >> 5, kk = idx & 31;
      __builtin_amdgcn_global_load_lds(GLB_CAST(&A[(size_t)(m0 + r) * 1024 + k0 + kk]),
                                       LDS_CAST(&As[idx]), 16, 0, 0);
      __builtin_amdgcn_global_load_lds(GLB_CAST(&Bt[(size_t)(n0 + r) * 1024 + k0 + kk]),
                                       LDS_CAST(&Bs[idx]), 16, 0, 0);
    }
    __syncthreads();
    short8 af[4], bfv[4];
    #pragma unroll
    for (int m = 0; m < 4; ++m)
      af[m] = *reinterpret_cast<const short8*>(&As[(wr + m * 16 + (lane & 15)) * 32 + (lane >> 4) * 8]);
    #pragma unroll
    for (int n = 0; n < 4; ++n)
      bfv[n] = *reinterpret_cast<const short8*>(&Bs[(wc + n * 16 + (lane & 15)) * 32 + (lane >> 4) * 8]);
    #pragma unroll
    for (int m = 0; m < 4; ++m)
      #pragma unroll
      for (int n = 0; n < 4; ++n)
        acc[m][n] = __builtin_amdgcn_mfma_f32_16x16x32_bf16(af[m], bfv[n], acc[m][n], 0, 0, 0);
    __syncthreads();
  }
}

// QKV projections. z=0: Q, z=1: K -> (B,H,T,64); z=2: V -> TRANSPOSED (B,H,64,T)
__global__ __launch_bounds__(256) void gemm_proj(
    const ushort_t* __restrict__ qb, const ushort_t* __restrict__ kb, const ushort_t* __restrict__ vb,
    const ushort_t* __restrict__ Wqb, const ushort_t* __restrict__ Wvb,
    const float* __restrict__ bq, const float* __restrict__ bvv,
    ushort_t* __restrict__ Qh, ushort_t* __restrict__ Kh, ushort_t* __restrict__ Vt) {
  __shared__ ushort_t As[128 * 32], Bs[128 * 32];
  const ushort_t* A; const ushort_t* Bt; const float* bias;
  if (blockIdx.z == 0)      { A = qb; Bt = Wqb; bias = bq;  }
  else if (blockIdx.z == 1) { A = kb; Bt = Wqb; bias = bq;  }
  else                      { A = vb; Bt = Wvb; bias = bvv; }
  const int m0 = blockIdx.y * 128, n0 = blockIdx.x * 128;
  f32x4 zero = {0.f, 0.f, 0.f, 0.f};
  f32x4 acc[4][4];
  #pragma unroll
  for (int m = 0; m < 4; ++m)
    #pragma unroll
    for (int n = 0; n < 4; ++n) acc[m][n] = zero;
  gemm_core(A, Bt, m0, n0, As, Bs, acc);
  const int lane = threadIdx.x & 63, wid = threadIdx.x >> 6;
  const int wr = (wid >> 1) * 64, wc = (wid & 1) * 64;
  if (blockIdx.z == 2) {
    #pragma unroll
    for (int m = 0; m < 4; ++m)
      #pragma unroll
      for (int n = 0; n < 4; ++n) {
        const int rowb = m0 + wr + m * 16 + (lane >> 4) * 4;
        const int col  = n0 + wc + n * 16 + (lane & 15);
        u16x4 pk;
        #pragma unroll
        for (int r4 = 0; r4 < 4; ++r4) pk[r4] = f2b(acc[m][n][r4] + bias[col]);
        const int bi = rowb >> 10, t = rowb & 1023;
        *reinterpret_cast<u16x4*>(
            &Vt[((size_t)(bi * 16 + (col >> 6)) * 64 + (col & 63)) * 1024 + t]) = pk;
      }
  } else {
    ushort_t* dst = (blockIdx.z == 0) ? Qh : Kh;
    #pragma unroll
    for (int m = 0; m < 4; ++m)
      #pragma unroll
      for (int n = 0; n < 4; ++n)
        #pragma unroll
        for (int r4 = 0; r4 < 4; ++r4) {
          const int row = m0 + wr + m * 16 + (lane >> 4) * 4 + r4;
          const int col = n0 + wc + n * 16 + (lane & 15);
          const float v = acc[m][n][r4] + bias[col];
          const int bi = row >> 10, t = row & 1023, h = col >> 6, dd = col & 63;
          dst[((size_t)(bi * 16 + h) * 1024 + t) * 64 + dd] = f2b(v);
        }
  }
}

// Output projection: x = concat@Wo^T + bo + query   -> bf16 xbuf
__global__ __launch_bounds__(256) void gemm_out(
    const ushort_t* __restrict__ A, const ushort_t* __restrict__ Bt,
    const float* __restrict__ bias, const float* __restrict__ resid,
    ushort_t* __restrict__ dstB) {
  __shared__ ushort_t As[128 * 32], Bs[128 * 32];
  const int m0 = blockIdx.y * 128, n0 = blockIdx.x * 128;
  f32x4 zero = {0.f, 0.f, 0.f, 0.f};
  f32x4 acc[4][4];
  #pragma unroll
  for (int m = 0; m < 4; ++m)
    #pragma unroll
    for (int n = 0; n < 4; ++n) acc[m][n] = zero;
  gemm_core(A, Bt, m0, n0, As, Bs, acc);
  const int lane = threadIdx.x & 63, wid = threadIdx.x >> 6;
  const int wr = (wid >> 1) * 64, wc = (wid & 1) * 64;
  #pragma unroll
  for (int m = 0; m < 4; ++m)
    #pragma unroll
    for (int n = 0; n < 4; ++n)
      #pragma unroll
      for (int r4 = 0; r4 < 4; ++r4) {
        const int row = m0 + wr + m * 16 + (lane >> 4) * 4 + r4;
        const int col = n0 + wc + n * 16 + (lane & 15);
        const size_t o = (size_t)row * 1024 + col;
        dstB[o] = f2b(acc[m][n][r4] + bias[col] + resid[o]);
      }
}

// ---------------------------------------------------------------------------
// Width-adaptive aligned LDS row access for Phase B.
// ---------------------------------------------------------------------------
template<int CH>
__device__ __forceinline__ void load_row(const ushort_t* __restrict__ Row, float (&s)[CH]) {
  constexpr int W = (CH % 8 == 0) ? 8 : (CH % 4 == 0) ? 4 : (CH % 2 == 0) ? 2 : 1;
  #pragma unroll
  for (int b = 0; b < CH / W; ++b) {
    if constexpr (W == 8) {
      const u16x8 t = *reinterpret_cast<const u16x8*>(&Row[b * 8]);
      #pragma unroll
      for (int e = 0; e < 8; ++e) s[b * 8 + e] = b2f(t[e]);
    } else if constexpr (W == 4) {
      const u16x4 t = *reinterpret_cast<const u16x4*>(&Row[b * 4]);
      #pragma unroll
      for (int e = 0; e < 4; ++e) s[b * 4 + e] = b2f(t[e]);
    } else if constexpr (W == 2) {
      const u16x2 t = *reinterpret_cast<const u16x2*>(&Row[b * 2]);
      s[b * 2] = b2f(t[0]); s[b * 2 + 1] = b2f(t[1]);
    } else {
      s[b] = b2f(Row[b]);
    }
  }
}

template<int CH>
__device__ __forceinline__ void store_row(ushort_t* __restrict__ Row,
                                          const float (&p)[CH], const float sc) {
  constexpr int W = (CH % 8 == 0) ? 8 : (CH % 4 == 0) ? 4 : (CH % 2 == 0) ? 2 : 1;
  #pragma unroll
  for (int b = 0; b < CH / W; ++b) {
    if constexpr (W == 8) {
      u16x8 o;
      #pragma unroll
      for (int e = 0; e < 8; ++e) o[e] = f2b(p[b * 8 + e] * sc);
      *reinterpret_cast<u16x8*>(&Row[b * 8]) = o;
    } else if constexpr (W == 4) {
      u16x4 o;
      #pragma unroll
      for (int e = 0; e < 4; ++e) o[e] = f2b(p[b * 4 + e] * sc);
      *reinterpret_cast<u16x4*>(&Row[b * 4]) = o;
    } else if constexpr (W == 2) {
      u16x2 o;
      o[0] = f2b(p[b * 2] * sc); o[1] = f2b(p[b * 2 + 1] * sc);
      *reinterpret_cast<u16x2*>(&Row[b * 2]) = o;
    } else {
      Row[b] = f2b(p[b] * sc);
    }
  }
}

// ---------------------------------------------------------------------------
// Phase B worker, CH columns per lane.  4 waves x 4 rows = 16 rows.
// Scores in LDS are pre-scaled by LOG2E (raw exp2 domain).
// ---------------------------------------------------------------------------
template<int CH>
__device__ __forceinline__ void phase_b(ushort_t* __restrict__ Sb, const int i0,
                                        const int w, const int lane, const float gamx) {
  const int c0 = CH * lane;
  for (int rr = 0; rr < 4; ++rr) {
    const int r = w * 4 + rr;
    const int i = i0 + r;
    ushort_t* __restrict__ Row = &Sb[r * 1032 + c0];
    if (i == 0) {                       // fully masked row -> P = 0
      #pragma unroll
      for (int e = 0; e < CH; ++e) Row[e] = 0;
      continue;
    }
    const int nact = min(max(i - c0, 0), CH);
    float s[CH], ev[CH];
    load_row<CH>(Row, s);
    // mask + first exp (no max-sub; scores are O(1)) + in-lane total
    float run = 0.f;
    #pragma unroll
    for (int e = 0; e < CH; ++e) {
      s[e] = (e < nact) ? s[e] : -__builtin_inff();
      ev[e] = EXP2F(s[e]);              // exact 0 for masked
      run += ev[e];
    }
    // wave-level inclusive suffix of lane totals -> Z1, exclusive tail
    float v = run;
    #pragma unroll
    for (int d = 1; d < 64; d <<= 1) {
      const float t = __shfl_down(v, d);
      v += (lane + d < 64) ? t : 0.f;
    }
    const float Z1 = __shfl(v, 0);
    float run2 = v - run;               // tail beyond this lane's span
    // gamma effect + second exp + fused z2/mm accumulation (single pass)
    const float g2 = -gamx * rsqrtf(Z1);
    const float posb = (float)(i - c0);
    float z2 = 0.f, mm = 0.f;
    #pragma unroll
    for (int e = CH - 1; e >= 0; --e) {
      const float t = fmaxf(run2 * (posb - (float)e), 0.f);
      run2 += ev[e];
      const float eff = fmaxf(EXP2F(g2 * sqrtf(t)), 1e-5f);
      const float p = EXP2F(s[e] * eff);   // -inf stays -inf -> p = 0
      ev[e] = p;
      z2 += p;
      mm = fmaxf(mm, p);
    }
    #pragma unroll
    for (int d = 32; d > 0; d >>= 1) {
      z2 += __shfl_xor(z2, d);
      mm = fmaxf(mm, __shfl_xor(mm, d));
    }
    const float sc = fminf(1.f / mm, 5.f / z2);   // maxout-combined normalizer
    store_row<CH>(Row, ev, sc);
  }
}

// ---------------------------------------------------------------------------
// Attention (R7 config).  grid = (64,64) remapped: one bh-octet per XCD,
// heaviest i0 first.  256 threads (4 waves).  S plain [16][1032] bf16.
// ---------------------------------------------------------------------------
__global__ __launch_bounds__(256, 4) void attn_kernel(
    const ushort_t* __restrict__ Qh, const ushort_t* __restrict__ Kh,
    const ushort_t* __restrict__ Vt, const float* __restrict__ gammas,
    ushort_t* __restrict__ concat) {
  __shared__ __align__(16) ushort_t Sb[16 * 1032];
  __shared__ __align__(16) ushort_t Qs[16 * 72];     // padded stride 72
  const int tid = threadIdx.x, lane = tid & 63, w = tid >> 6;
  const int flat = blockIdx.x + (blockIdx.y << 6);
  const int bh = ((flat & 7) << 3) | (flat >> 9);
  const int i0 = (63 - ((flat >> 3) & 63)) << 4;     // heaviest first
  const int bi = bh >> 4, h = bh & 15;
  const size_t base = (size_t)bh * (1024 * 64);

  { // stage Q tile (16 rows x 64)
    const int r = tid >> 4, d = (tid & 15) * 4;
    *reinterpret_cast<u16x4*>(&Qs[r * 72 + d]) =
        *reinterpret_cast<const u16x4*>(&Qh[base + (size_t)(i0 + r) * 64 + d]);
  }
  __syncthreads();

  // ---- Phase A: scores * (0.125*LOG2E) -> bf16 S ----
  const int upper = i0 + 16;
  for (int nt = 0; nt < 16; ++nt) {
    const int colbase = (nt * 4 + w) * 16;
    if (colbase >= upper) break;
    f32x4 acc = {0.f, 0.f, 0.f, 0.f};
    #pragma unroll
    for (int kt = 0; kt < 2; ++kt) {
      const short8 a = *reinterpret_cast<const short8*>(
          &Qs[(lane & 15) * 72 + kt * 32 + (lane >> 4) * 8]);
      const short8 bb = *reinterpret_cast<const short8*>(
          &Kh[base + (size_t)(colbase + (lane & 15)) * 64 + kt * 32 + (lane >> 4) * 8]);
      acc = __builtin_amdgcn_mfma_f32_16x16x32_bf16(a, bb, acc, 0, 0, 0);
    }
    const int j = colbase + (lane & 15);
    #pragma unroll
    for (int r4 = 0; r4 < 4; ++r4) {
      const int rf = (lane >> 4) * 4 + r4;
      Sb[rf * 1032 + j] = f2b(acc[r4] * (0.125f * LOG2E));
    }
  }
  __syncthreads();

  // ---- Phase B: exact-even causal tiering, 4 rows/wave ----
  const float gamx = fabsf(gammas[h]) * LOG2E;
  const int chp = (upper + 63) >> 6;        // col-blocks needed (block-uniform)
  switch (chp) {
    case 1:           phase_b<1 >(Sb, i0, w, lane, gamx); break;
    case 2:           phase_b<2 >(Sb, i0, w, lane, gamx); break;
    case 3: case 4:   phase_b<4 >(Sb, i0, w, lane, gamx); break;
    case 5: case 6:   phase_b<6 >(Sb, i0, w, lane, gamx); break;
    case 7: case 8:   phase_b<8 >(Sb, i0, w, lane, gamx); break;
    case 9: case 10:  phase_b<10>(Sb, i0, w, lane, gamx); break;
    case 11: case 12: phase_b<12>(Sb, i0, w, lane, gamx); break;
    case 13: case 14: phase_b<14>(Sb, i0, w, lane, gamx); break;
    default:          phase_b<16>(Sb, i0, w, lane, gamx); break;
  }
  __syncthreads();

  // ---- Phase C: PV via MFMA.  wave w -> d-tile d0 = w*16 ----
  {
    const int d0 = w * 16;
    const int arow = lane & 15;
    const ushort_t* Prow = &Sb[arow * 1032];
    const ushort_t* Vrow = Vt + base + (size_t)(d0 + arow) * 1024;
    const int kmax = (upper + 31) & ~31;
    f32x4 acc = {0.f, 0.f, 0.f, 0.f};
    for (int k0 = 0; k0 < kmax; k0 += 32) {
      const short8 a = *reinterpret_cast<const short8*>(&Prow[k0 + (lane >> 4) * 8]);
      const short8 bb = *reinterpret_cast<const short8*>(&Vrow[k0 + (lane >> 4) * 8]);
      acc = __builtin_amdgcn_mfma_f32_16x16x32_bf16(a, bb, acc, 0, 0, 0);
    }
    #pragma unroll
    for (int r4 = 0; r4 < 4; ++r4) {
      const int row = (lane >> 4) * 4 + r4;
      const int i = i0 + row;
      concat[((size_t)(bi * 1024 + i)) * 1024 + h * 64 + d0 + arow] = f2b(acc[r4]);
    }
  }
}

// ---------------------------------------------------------------------------
// LayerNorm over D=1024, bf16 input row, f32 output.
// ---------------------------------------------------------------------------
__global__ __launch_bounds__(256) void ln_kernel(const ushort_t* __restrict__ x,
                                                 const float* __restrict__ g,
                                                 const float* __restrict__ bb,
                                                 float* __restrict__ out) {
  const int row = blockIdx.x, tid = threadIdx.x, lane = tid & 63, w = tid >> 6;
  const u16x4 xv = reinterpret_cast<const u16x4*>(x + (size_t)row * 1024)[tid];
  float v0 = b2f(xv[0]), v1 = b2f(xv[1]), v2 = b2f(xv[2]), v3 = b2f(xv[3]);
  float s = v0 + v1 + v2 + v3;
  float q = v0 * v0 + v1 * v1 + v2 * v2 + v3 * v3;
  s = wave_sum(s); q = wave_sum(q);
  __shared__ float ps[4], pq[4];
  if (lane == 0) { ps[w] = s; pq[w] = q; }
  __syncthreads();
  const float ts = ps[0] + ps[1] + ps[2] + ps[3];
  const float tq = pq[0] + pq[1] + pq[2] + pq[3];
  const float mu = ts * (1.f / 1024.f);
  const float inv = rsqrtf(tq * (1.f / 1024.f) - mu * mu + 1e-5f);
  const float4 gv = reinterpret_cast<const float4*>(g)[tid];
  const float4 bv = reinterpret_cast<const float4*>(bb)[tid];
  float4 o;
  o.x = (v0 - mu) * inv * gv.x + bv.x;
  o.y = (v1 - mu) * inv * gv.y + bv.y;
  o.z = (v2 - mu) * inv * gv.z + bv.z;
  o.w = (v3 - mu) * inv * gv.w + bv.w;
  reinterpret_cast<float4*>(out + (size_t)row * 1024)[tid] = o;
}

// ---------------------------------------------------------------------------
extern "C" void kernel_launch(void* const* d_in, const int* in_sizes, int n_in,
                              void* d_out, int out_size, void* d_ws, size_t ws_size,
                              hipStream_t stream) {
  (void)in_sizes; (void)n_in; (void)out_size; (void)ws_size;
  const float* query  = (const float*)d_in[0];
  const float* key    = (const float*)d_in[1];
  const float* values = (const float*)d_in[2];
  const float* Wq     = (const float*)d_in[3];
  const float* bq     = (const float*)d_in[4];
  const float* Wv     = (const float*)d_in[5];
  const float* bv     = (const float*)d_in[6];
  const float* Wo     = (const float*)d_in[7];
  const float* bo     = (const float*)d_in[8];
  const float* gammas = (const float*)d_in[9];
  const float* ln_g   = (const float*)d_in[10];
  const float* ln_b   = (const float*)d_in[11];
  float* out = (float*)d_out;

  const size_t NT = 4096ull * 1024;
  const size_t NW = 1024ull * 1024;
  char* p = (char*)d_ws;
  ushort_t* qb  = (ushort_t*)p; p += NT * 2;
  ushort_t* kb  = (ushort_t*)p; p += NT * 2;
  ushort_t* vb  = (ushort_t*)p; p += NT * 2;
  ushort_t* Wqb = (ushort_t*)p; p += NW * 2;
  ushort_t* Wvb = (ushort_t*)p; p += NW * 2;
  ushort_t* Wob = (ushort_t*)p; p += NW * 2;
  ushort_t* Qh  = (ushort_t*)p; p += NT * 2;
  ushort_t* Kh  = (ushort_t*)p; p += NT * 2;
  ushort_t* Vt  = (ushort_t*)p; p += NT * 2;
  ushort_t* concat = vb;                // free after gemm_proj
  ushort_t* xbuf   = qb;                // bf16 x, free after gemm_proj

  conv6_f32_bf16<<<dim3(4096, 6), 256, 0, stream>>>(
      query, key, values, Wq, Wv, Wo, qb, kb, vb, Wqb, Wvb, Wob,
      (int)(NT / 4), (int)(NW / 4));

  gemm_proj<<<dim3(8, 32, 3), 256, 0, stream>>>(qb, kb, vb, Wqb, Wvb, bq, bv, Qh, Kh, Vt);
  attn_kernel<<<dim3(64, 64), 256, 0, stream>>>(Qh, Kh, Vt, gammas, concat);
  gemm_out<<<dim3(8, 32), 256, 0, stream>>>(concat, Wob, bo, query, xbuf);
  ln_kernel<<<4096, 256, 0, stream>>>(xbuf, ln_g, ln_b, out);
}